// Round 6
// baseline (319.165 us; speedup 1.0000x reference)
//
#include <hip/hip_runtime.h>

#define Ssz 2048
#define Dd  128
#define Hh  8
#define Bb  2
#define HDp 1024

typedef unsigned short u16;
typedef unsigned int   u32;

__device__ __forceinline__ float bflo(u32 w) { return __uint_as_float(w << 16); }
__device__ __forceinline__ float bfhi(u32 w) { return __uint_as_float(w & 0xffff0000u); }
__device__ __forceinline__ u16 f2bf(float f) {
    u32 x = __float_as_uint(f);
    u32 r = x + 0x7fffu + ((x >> 16) & 1u);
    return (u16)(r >> 16);
}

// ---------------- Projection: [4096x128] @ [128x3072] (3 fused GEMMs) --------
// fp32 inputs; fp32 accumulate; writes Q/K/V projections as bf16 [B,H,S,D] to ws.
// grid (64 m-tiles, 48 n-tiles), 256 threads, 64x64 tile, 4x4 micro-tile.
__global__ __launch_bounds__(256, 2)
void proj_kernel(const float* __restrict__ q, const float* __restrict__ k,
                 const float* __restrict__ v, const float* __restrict__ Wq,
                 const float* __restrict__ Wk, const float* __restrict__ Wv,
                 u16* __restrict__ Qp, u16* __restrict__ Kp, u16* __restrict__ Vp)
{
    __shared__ float XsT[128][64];   // X transposed: XsT[k][m]
    __shared__ float Ws[128][68];    // W row-major, padded

    const int t  = threadIdx.x;
    const int m0 = blockIdx.x << 6;
    const int n0 = blockIdx.y << 6;
    const int which = n0 >> 10;                 // 0=Q,1=K,2=V
    const float* x = (which == 0) ? q  : (which == 1) ? k  : v;
    const float* W = (which == 0) ? Wq : (which == 1) ? Wk : Wv;
    u16* dst       = (which == 0) ? Qp : (which == 1) ? Kp : Vp;
    const int nc0 = n0 & 1023;

    // stage X tile (64 rows x 128 k), transposed into LDS
    {
        const int row = t >> 2;
        const int kb  = (t & 3) << 5;
        const float* src = x + (size_t)(m0 + row) * Dd + kb;
        #pragma unroll
        for (int u = 0; u < 8; ++u) {
            float4 xv = *(const float4*)(src + (u << 2));
            const int kk = kb + (u << 2);
            XsT[kk+0][row] = xv.x; XsT[kk+1][row] = xv.y;
            XsT[kk+2][row] = xv.z; XsT[kk+3][row] = xv.w;
        }
    }
    // stage W tile (128 k x 64 n)
    {
        const int kr = t >> 1;
        const int nb = (t & 1) << 5;
        const float* src = W + (size_t)kr * HDp + nc0 + nb;
        #pragma unroll
        for (int u = 0; u < 8; ++u) {
            float4 wv = *(const float4*)(src + (u << 2));
            const int nn = nb + (u << 2);
            Ws[kr][nn+0] = wv.x; Ws[kr][nn+1] = wv.y;
            Ws[kr][nn+2] = wv.z; Ws[kr][nn+3] = wv.w;
        }
    }
    __syncthreads();

    const int ty = t >> 4, tx = t & 15;
    float acc[4][4] = {};
    #pragma unroll 8
    for (int kk = 0; kk < 128; ++kk) {
        float4 a  = *(const float4*)&XsT[kk][ty << 2];
        float4 b4 = *(const float4*)&Ws[kk][tx << 2];
        acc[0][0] += a.x*b4.x; acc[0][1] += a.x*b4.y; acc[0][2] += a.x*b4.z; acc[0][3] += a.x*b4.w;
        acc[1][0] += a.y*b4.x; acc[1][1] += a.y*b4.y; acc[1][2] += a.y*b4.z; acc[1][3] += a.y*b4.w;
        acc[2][0] += a.z*b4.x; acc[2][1] += a.z*b4.y; acc[2][2] += a.z*b4.z; acc[2][3] += a.z*b4.w;
        acc[3][0] += a.w*b4.x; acc[3][1] += a.w*b4.y; acc[3][2] += a.w*b4.z; acc[3][3] += a.w*b4.w;
    }

    #pragma unroll
    for (int r = 0; r < 4; ++r) {
        const int m  = m0 + (ty << 2) + r;
        const int bb = m >> 11, ss = m & 2047;
        const int nc = nc0 + (tx << 2);
        const int hh = nc >> 7, dd = nc & 127;
        u16* o = dst + ((size_t)((bb*Hh + hh)*Ssz + ss)) * Dd + dd;
        u32 w0 = (u32)f2bf(acc[r][0]) | ((u32)f2bf(acc[r][1]) << 16);
        u32 w1 = (u32)f2bf(acc[r][2]) | ((u32)f2bf(acc[r][3]) << 16);
        *(uint2*)o = make_uint2(w0, w1);
    }
}

// ---------------- Windowed flash attention ----------------
// Effective window after combining causal + RPE masks: j in [i-511, i-1].
// Row i=0 has no valid keys -> softmax degenerates to one-hot at j=0 -> out = V[0].
// block = (q-tile of 64 rows, h, b); 256 thr; 32-key chunks. OUTPUT IS FP32.
__global__ __launch_bounds__(256, 2)
void attn_kernel(const u16* __restrict__ Qp, const u16* __restrict__ Kp,
                 const u16* __restrict__ Vp, const float* __restrict__ emb,
                 float* __restrict__ out)
{
    __shared__ float QsT[128][64];
    __shared__ float KsT[128][36];
    __shared__ float Vs[32][128];
    __shared__ float Ps[64][36];
    __shared__ float embs[512];

    const int t  = threadIdx.x;
    const int i0 = blockIdx.x << 6;
    const int h  = blockIdx.y;
    const int b  = blockIdx.z;
    const size_t hoff = (size_t)(b*Hh + h) * Ssz * Dd;
    const u16* Qh = Qp + hoff;
    const u16* Kh = Kp + hoff;
    const u16* Vh = Vp + hoff;

    embs[t]       = emb[t];
    embs[t + 256] = emb[t + 256];

    {   // stage Q tile transposed (bf16 -> f32)
        const int row = t >> 2;
        const int kb  = (t & 3) << 5;
        const u16* src = Qh + (size_t)(i0 + row) * Dd + kb;
        #pragma unroll
        for (int u = 0; u < 4; ++u) {
            uint4 qv = *(const uint4*)(src + (u << 3));
            const int kk = kb + (u << 3);
            QsT[kk+0][row] = bflo(qv.x); QsT[kk+1][row] = bfhi(qv.x);
            QsT[kk+2][row] = bflo(qv.y); QsT[kk+3][row] = bfhi(qv.y);
            QsT[kk+4][row] = bflo(qv.z); QsT[kk+5][row] = bfhi(qv.z);
            QsT[kk+6][row] = bflo(qv.w); QsT[kk+7][row] = bfhi(qv.w);
        }
    }

    const int ty = t >> 3;   // 0..31
    const int tx = t & 7;    // 0..7
    const float scale = 0.08838834764831845f;  // 1/sqrt(128)

    float m_r[2] = {-1e30f, -1e30f};
    float l_r[2] = {0.f, 0.f};
    float acc[2][16] = {};

    const int cbeg = (i0 >= 512) ? (i0 - 512) : 0;
    const int cend = i0 + 32;
    for (int j0 = cbeg; j0 <= cend; j0 += 32) {
        __syncthreads();
        {   // stage K (transposed) and V chunk: 32 rows x 128, bf16 -> f32
            const int jr = t >> 3;
            const int kb = (t & 7) << 4;
            const u16* ksrc = Kh + (size_t)(j0 + jr) * Dd + kb;
            const u16* vsrc = Vh + (size_t)(j0 + jr) * Dd + kb;
            #pragma unroll
            for (int u = 0; u < 2; ++u) {
                const int kk = kb + (u << 3);
                uint4 kv = *(const uint4*)(ksrc + (u << 3));
                KsT[kk+0][jr] = bflo(kv.x); KsT[kk+1][jr] = bfhi(kv.x);
                KsT[kk+2][jr] = bflo(kv.y); KsT[kk+3][jr] = bfhi(kv.y);
                KsT[kk+4][jr] = bflo(kv.z); KsT[kk+5][jr] = bfhi(kv.z);
                KsT[kk+6][jr] = bflo(kv.w); KsT[kk+7][jr] = bfhi(kv.w);
                uint4 vv = *(const uint4*)(vsrc + (u << 3));
                float4 v0 = make_float4(bflo(vv.x), bfhi(vv.x), bflo(vv.y), bfhi(vv.y));
                float4 v1 = make_float4(bflo(vv.z), bfhi(vv.z), bflo(vv.w), bfhi(vv.w));
                *(float4*)&Vs[jr][kk]     = v0;
                *(float4*)&Vs[jr][kk + 4] = v1;
            }
        }
        __syncthreads();

        // S tile: 2 rows x 4 cols per thread, K=128 from LDS
        float sa[2][4] = {};
        #pragma unroll 8
        for (int kk = 0; kk < 128; ++kk) {
            float2 a  = *(const float2*)&QsT[kk][ty << 1];
            float4 b4 = *(const float4*)&KsT[kk][tx << 2];
            sa[0][0] += a.x*b4.x; sa[0][1] += a.x*b4.y; sa[0][2] += a.x*b4.z; sa[0][3] += a.x*b4.w;
            sa[1][0] += a.y*b4.x; sa[1][1] += a.y*b4.y; sa[1][2] += a.y*b4.z; sa[1][3] += a.y*b4.w;
        }

        // mask + RPE bias + online softmax (per row, reduced over the 8 tx lanes)
        #pragma unroll
        for (int r = 0; r < 2; ++r) {
            const int ig = i0 + (ty << 1) + r;
            float sv[4];
            #pragma unroll
            for (int c = 0; c < 4; ++c) {
                const int jg = j0 + (tx << 2) + c;
                const int dd = ig - jg;                    // valid iff 1..511
                const bool valid = (dd >= 1) && (dd <= 511);
                sv[c] = valid ? (sa[r][c] * scale + embs[dd - 1]) : -1e30f;
            }
            float mx = fmaxf(fmaxf(sv[0], sv[1]), fmaxf(sv[2], sv[3]));
            mx = fmaxf(mx, __shfl_xor(mx, 1));
            mx = fmaxf(mx, __shfl_xor(mx, 2));
            mx = fmaxf(mx, __shfl_xor(mx, 4));
            const float mnew  = fmaxf(m_r[r], mx);
            const float alpha = __expf(m_r[r] - mnew);
            float ps[4]; float rs = 0.f;
            #pragma unroll
            for (int c = 0; c < 4; ++c) {
                ps[c] = (sv[c] > -1e29f) ? __expf(sv[c] - mnew) : 0.f;
                rs += ps[c];
            }
            rs += __shfl_xor(rs, 1);
            rs += __shfl_xor(rs, 2);
            rs += __shfl_xor(rs, 4);
            l_r[r] = l_r[r] * alpha + rs;
            m_r[r] = mnew;
            *(float4*)&Ps[(ty << 1) + r][tx << 2] = make_float4(ps[0], ps[1], ps[2], ps[3]);
            #pragma unroll
            for (int c = 0; c < 16; ++c) acc[r][c] *= alpha;
        }
        __syncthreads();   // Ps hand-off (cheap insurance; see round-3 note)

        // PV: acc[2][16] += P[2][32] * Vs[32][16tx..]
        #pragma unroll 4
        for (int j = 0; j < 32; ++j) {
            const float p0 = Ps[(ty << 1) + 0][j];
            const float p1 = Ps[(ty << 1) + 1][j];
            const float* vr = &Vs[j][tx << 4];
            #pragma unroll
            for (int c4 = 0; c4 < 4; ++c4) {
                float4 vv = *(const float4*)(vr + (c4 << 2));
                acc[0][c4*4+0] += p0*vv.x; acc[0][c4*4+1] += p0*vv.y;
                acc[0][c4*4+2] += p0*vv.z; acc[0][c4*4+3] += p0*vv.w;
                acc[1][c4*4+0] += p1*vv.x; acc[1][c4*4+1] += p1*vv.y;
                acc[1][c4*4+2] += p1*vv.z; acc[1][c4*4+3] += p1*vv.w;
            }
        }
    }

    // epilogue (FP32 OUT): out[b, i, h*128 + c] = acc / l   (row 0: out = V[0])
    #pragma unroll
    for (int r = 0; r < 2; ++r) {
        const int ig = i0 + (ty << 1) + r;
        float* o = out + ((size_t)(b * Ssz + ig)) * HDp + h * Dd + (tx << 4);
        float res[16];
        if (ig == 0) {
            const u16* vr = Vh + (tx << 4);
            uint4 a0 = *(const uint4*)(vr);
            uint4 a1 = *(const uint4*)(vr + 8);
            res[0]=bflo(a0.x); res[1]=bfhi(a0.x); res[2]=bflo(a0.y); res[3]=bfhi(a0.y);
            res[4]=bflo(a0.z); res[5]=bfhi(a0.z); res[6]=bflo(a0.w); res[7]=bfhi(a0.w);
            res[8]=bflo(a1.x); res[9]=bfhi(a1.x); res[10]=bflo(a1.y); res[11]=bfhi(a1.y);
            res[12]=bflo(a1.z); res[13]=bfhi(a1.z); res[14]=bflo(a1.w); res[15]=bfhi(a1.w);
        } else {
            const float inv = 1.0f / l_r[r];
            #pragma unroll
            for (int c = 0; c < 16; ++c) res[c] = acc[r][c] * inv;
        }
        #pragma unroll
        for (int c4 = 0; c4 < 4; ++c4)
            *(float4*)(o + (c4 << 2)) = make_float4(res[c4*4+0], res[c4*4+1],
                                                    res[c4*4+2], res[c4*4+3]);
    }
}

extern "C" void kernel_launch(void* const* d_in, const int* in_sizes, int n_in,
                              void* d_out, int out_size, void* d_ws, size_t ws_size,
                              hipStream_t stream)
{
    const float* q   = (const float*)d_in[0];
    const float* k   = (const float*)d_in[1];
    const float* v   = (const float*)d_in[2];
    const float* Wq  = (const float*)d_in[3];
    const float* Wk  = (const float*)d_in[4];
    const float* Wv  = (const float*)d_in[5];
    const float* emb = (const float*)d_in[6];
    float* out = (float*)d_out;

    const size_t per = (size_t)Bb * Hh * Ssz * Dd;   // 4.19M elements (bf16)
    u16* Qp = (u16*)d_ws;
    u16* Kp = Qp + per;
    u16* Vp = Kp + per;

    dim3 g1(64, 48), blk(256);
    proj_kernel<<<g1, blk, 0, stream>>>(q, k, v, Wq, Wk, Wv, Qp, Kp, Vp);

    dim3 g2(Ssz / 64, Hh, Bb);
    attn_kernel<<<g2, blk, 0, stream>>>(Qp, Kp, Vp, emb, out);
}

// Round 8
// 156.345 us; speedup vs baseline: 2.0414x; 2.0414x over previous
//
#include <hip/hip_runtime.h>

#define Ssz 2048
#define Dd  128
#define Hh  8
#define Bb  2
#define HDp 1024

typedef unsigned short u16;
typedef unsigned int   u32;

typedef __attribute__((ext_vector_type(8))) short bf16x8;   // 8 bf16 = 4 VGPRs
typedef __attribute__((ext_vector_type(4))) float f32x4;    // C/D frag

__device__ __forceinline__ float bflo(u32 w) { return __uint_as_float(w << 16); }
__device__ __forceinline__ u16 f2bf(float f) {
    u32 x = __float_as_uint(f);
    u32 r = x + 0x7fffu + ((x >> 16) & 1u);
    return (u16)(r >> 16);
}
__device__ __forceinline__ u32 pack2(float a, float b) {
    return (u32)f2bf(a) | ((u32)f2bf(b) << 16);
}

// ---------------- Projection (MFMA): [4096x128] @ [128x3072] ----------------
// fp32 in; bf16 LDS staging; mfma_f32_16x16x32_bf16; Q/K written row-major
// [b,h,s,d], V written d-major [b,h,d,s] (so attn PV B-frags are contiguous).
__global__ __launch_bounds__(256, 3)
void proj_kernel(const float* __restrict__ q, const float* __restrict__ k,
                 const float* __restrict__ v, const float* __restrict__ Wq,
                 const float* __restrict__ Wk, const float* __restrict__ Wv,
                 u16* __restrict__ Qp, u16* __restrict__ Kp, u16* __restrict__ VpT)
{
    __shared__ __align__(16) u16 Xs[64][136];   // X tile rows, pad 136 (odd word stride)
    __shared__ __align__(16) u16 Wt[64][136];   // W^T: Wt[n][k]

    const int t  = threadIdx.x;
    const int m0 = blockIdx.x << 6;
    const int n0 = blockIdx.y << 6;
    const int which = n0 >> 10;                 // 0=Q,1=K,2=V
    const float* x = (which == 0) ? q  : (which == 1) ? k  : v;
    const float* W = (which == 0) ? Wq : (which == 1) ? Wk : Wv;
    const int nc0 = n0 & 1023;

    {   // stage X (64x128) f32->bf16, row-major
        const int row = t >> 2, seg = t & 3;
        const float* src = x + (size_t)(m0 + row) * Dd + seg * 32;
        u16* dl = &Xs[row][seg * 32];
        #pragma unroll
        for (int u = 0; u < 4; ++u) {
            float4 a = *(const float4*)(src + u * 8);
            float4 b = *(const float4*)(src + u * 8 + 4);
            *(uint4*)(dl + u * 8) = make_uint4(pack2(a.x, a.y), pack2(a.z, a.w),
                                               pack2(b.x, b.y), pack2(b.z, b.w));
        }
    }
    {   // stage W^T (64n x 128k) f32->bf16
        const int kr = t >> 1, seg = t & 1;
        const float* src = W + (size_t)kr * HDp + nc0 + seg * 32;
        #pragma unroll
        for (int u = 0; u < 8; ++u) {
            float4 a = *(const float4*)(src + u * 4);
            Wt[seg * 32 + u * 4 + 0][kr] = f2bf(a.x);
            Wt[seg * 32 + u * 4 + 1][kr] = f2bf(a.y);
            Wt[seg * 32 + u * 4 + 2][kr] = f2bf(a.z);
            Wt[seg * 32 + u * 4 + 3][kr] = f2bf(a.w);
        }
    }
    __syncthreads();

    const int lane = t & 63, w = t >> 6;
    const int L15 = lane & 15, quad = lane >> 4;

    f32x4 acc[4] = {};
    #pragma unroll
    for (int ks = 0; ks < 4; ++ks) {
        bf16x8 a = *(const bf16x8*)&Xs[16 * w + L15][ks * 32 + quad * 8];
        #pragma unroll
        for (int nt = 0; nt < 4; ++nt) {
            bf16x8 b = *(const bf16x8*)&Wt[nt * 16 + L15][ks * 32 + quad * 8];
            acc[nt] = __builtin_amdgcn_mfma_f32_16x16x32_bf16(a, b, acc[nt], 0, 0, 0);
        }
    }

    #pragma unroll
    for (int nt = 0; nt < 4; ++nt) {
        const int nc = nc0 + nt * 16 + L15;
        const int hh = nc >> 7, dd = nc & 127;
        #pragma unroll
        for (int r = 0; r < 4; ++r) {
            const int m  = m0 + 16 * w + quad * 4 + r;
            const int bb = m >> 11, ss = m & 2047;
            const u16 val = f2bf(acc[nt][r]);
            if (which == 0)
                Qp[((size_t)((bb * Hh + hh) * Ssz + ss)) * Dd + dd] = val;
            else if (which == 1)
                Kp[((size_t)((bb * Hh + hh) * Ssz + ss)) * Dd + dd] = val;
            else
                VpT[((size_t)((bb * Hh + hh) * Dd + dd)) * Ssz + ss] = val;
        }
    }
}

// ---------------- Windowed flash attention (MFMA) ----------------
// Window after combining causal+RPE masks: j in [i-511, i-1]; row 0 -> V[0].
// Block = 64 Q-rows x (h,b); 4 waves; wave w owns rows 16w..16w+15.
__global__ __launch_bounds__(256, 3)
void attn_kernel(const u16* __restrict__ Qp, const u16* __restrict__ Kp,
                 const u16* __restrict__ VpT, const float* __restrict__ emb,
                 float* __restrict__ out)
{
    __shared__ __align__(16) u16 Qls[64][136];  // Q tile, row-major bf16
    __shared__ __align__(16) u16 Ks[32][136];   // K chunk, row-major
    __shared__ __align__(16) u16 Vt[128][40];   // V chunk, d-major [d][j]
    __shared__ __align__(16) u16 Ps[64][40];    // P tile [row][j]
    __shared__ float embs[512];

    const int t  = threadIdx.x;
    const int i0 = blockIdx.x << 6;
    const int h  = blockIdx.y;
    const int b  = blockIdx.z;
    const size_t hoff = (size_t)(b * Hh + h) * Ssz * Dd;
    const u16* Qh = Qp + hoff;
    const u16* Kh = Kp + hoff;
    const u16* Vh = VpT + hoff;     // d-major: [d][s]

    embs[t] = emb[t]; embs[t + 256] = emb[t + 256];

    {   // stage Q rows (raw bf16 copy, 64x128)
        const int row = t >> 2, seg = t & 3;
        const u16* src = Qh + (size_t)(i0 + row) * Dd + seg * 32;
        u16* dl = &Qls[row][seg * 32];
        #pragma unroll
        for (int u = 0; u < 4; ++u)
            *(uint4*)(dl + u * 8) = *(const uint4*)(src + u * 8);
    }
    __syncthreads();

    const int lane = t & 63, w = t >> 6;
    const int L15 = lane & 15, quad = lane >> 4;

    // Q A-fragments, resident for the whole kernel: A[m=L15][k=quad*8+j]
    bf16x8 qf[4];
    #pragma unroll
    for (int ks = 0; ks < 4; ++ks)
        qf[ks] = *(const bf16x8*)&Qls[16 * w + L15][ks * 32 + quad * 8];

    const float scale = 0.08838834764831845f;   // 1/sqrt(128)
    float m_r[4], l_r[4];
    #pragma unroll
    for (int r = 0; r < 4; ++r) { m_r[r] = -1e30f; l_r[r] = 0.f; }
    f32x4 acc_o[8] = {};

    const int cbeg = (i0 >= 512) ? (i0 - 512) : 0;
    const int cend = i0 + 32;
    for (int j0 = cbeg; j0 <= cend; j0 += 32) {
        __syncthreads();                        // prior PV reads done before restage
        {   // stage K chunk: 32 rows x 128 (16 u16 per thread — FULL coverage)
            const int jr = t >> 3, seg = t & 7;
            const u16* src = Kh + (size_t)(j0 + jr) * Dd + seg * 16;
            u16* dl = &Ks[jr][seg * 16];
            *(uint4*)(dl)     = *(const uint4*)(src);
            *(uint4*)(dl + 8) = *(const uint4*)(src + 8);
        }
        {   // stage V^T chunk from d-major global: 128 x 32
            #pragma unroll
            for (int p = 0; p < 2; ++p) {
                const int d_ = (t >> 2) + 64 * p, seg = t & 3;
                *(uint4*)&Vt[d_][seg * 8] =
                    *(const uint4*)(Vh + (size_t)d_ * Ssz + j0 + seg * 8);
            }
        }
        __syncthreads();

        // S = Q·K^T  (16 rows x 32 cols per wave)
        f32x4 acc_s[2] = {};
        #pragma unroll
        for (int ks = 0; ks < 4; ++ks) {
            #pragma unroll
            for (int n16 = 0; n16 < 2; ++n16) {
                bf16x8 bk = *(const bf16x8*)&Ks[n16 * 16 + L15][ks * 32 + quad * 8];
                acc_s[n16] = __builtin_amdgcn_mfma_f32_16x16x32_bf16(qf[ks], bk, acc_s[n16], 0, 0, 0);
            }
        }

        // mask + RPE bias + online softmax (C-layout: row=quad*4+r, col=n16*16+L15)
        #pragma unroll
        for (int r = 0; r < 4; ++r) {
            const int ig = i0 + 16 * w + quad * 4 + r;
            const int d0 = ig - (j0 + L15);
            const int d1 = d0 - 16;
            const int i0x = min(max(d0 - 1, 0), 511);
            const int i1x = min(max(d1 - 1, 0), 511);
            const float sv0 = (d0 >= 1 && d0 <= 511) ? (acc_s[0][r] * scale + embs[i0x]) : -1e30f;
            const float sv1 = (d1 >= 1 && d1 <= 511) ? (acc_s[1][r] * scale + embs[i1x]) : -1e30f;
            float mx = fmaxf(sv0, sv1);
            mx = fmaxf(mx, __shfl_xor(mx, 1));
            mx = fmaxf(mx, __shfl_xor(mx, 2));
            mx = fmaxf(mx, __shfl_xor(mx, 4));
            mx = fmaxf(mx, __shfl_xor(mx, 8));
            const float mnew  = fmaxf(m_r[r], mx);
            const float alpha = __expf(m_r[r] - mnew);
            m_r[r] = mnew;
            const float p0 = (sv0 > -1e29f) ? __expf(sv0 - mnew) : 0.f;
            const float p1 = (sv1 > -1e29f) ? __expf(sv1 - mnew) : 0.f;
            float rs = p0 + p1;
            rs += __shfl_xor(rs, 1);
            rs += __shfl_xor(rs, 2);
            rs += __shfl_xor(rs, 4);
            rs += __shfl_xor(rs, 8);
            l_r[r] = l_r[r] * alpha + rs;
            #pragma unroll
            for (int nt = 0; nt < 8; ++nt) acc_o[nt][r] *= alpha;
            Ps[16 * w + quad * 4 + r][L15]      = f2bf(p0);
            Ps[16 * w + quad * 4 + r][16 + L15] = f2bf(p1);
        }
        __syncthreads();    // P C-layout -> A-layout hand-off through LDS

        // O += P·V   (A = P[m=L15][k=quad*8+j], B = V[k][n=L15] from Vt)
        bf16x8 ap = *(const bf16x8*)&Ps[16 * w + L15][quad * 8];
        #pragma unroll
        for (int nt = 0; nt < 8; ++nt) {
            bf16x8 bv = *(const bf16x8*)&Vt[nt * 16 + L15][quad * 8];
            acc_o[nt] = __builtin_amdgcn_mfma_f32_16x16x32_bf16(ap, bv, acc_o[nt], 0, 0, 0);
        }
    }

    // epilogue (fp32 out): out[b, ig, h*128 + d] = acc / l ; row 0 -> V[:,0]
    #pragma unroll
    for (int r = 0; r < 4; ++r) {
        const int ig = i0 + 16 * w + quad * 4 + r;
        float* o = out + ((size_t)(b * Ssz + ig)) * HDp + h * Dd;
        if (ig == 0) {
            #pragma unroll
            for (int nt = 0; nt < 8; ++nt)
                o[nt * 16 + L15] = bflo((u32)Vh[(size_t)(nt * 16 + L15) * Ssz]);
        } else {
            const float inv = 1.0f / l_r[r];
            #pragma unroll
            for (int nt = 0; nt < 8; ++nt)
                o[nt * 16 + L15] = acc_o[nt][r] * inv;
        }
    }
}

extern "C" void kernel_launch(void* const* d_in, const int* in_sizes, int n_in,
                              void* d_out, int out_size, void* d_ws, size_t ws_size,
                              hipStream_t stream)
{
    const float* q   = (const float*)d_in[0];
    const float* k   = (const float*)d_in[1];
    const float* v   = (const float*)d_in[2];
    const float* Wq  = (const float*)d_in[3];
    const float* Wk  = (const float*)d_in[4];
    const float* Wv  = (const float*)d_in[5];
    const float* emb = (const float*)d_in[6];
    float* out = (float*)d_out;

    const size_t per = (size_t)Bb * Hh * Ssz * Dd;   // 4.19M bf16 elements each
    u16* Qp  = (u16*)d_ws;
    u16* Kp  = Qp + per;
    u16* VpT = Kp + per;

    dim3 g1(64, 48), blk(256);
    proj_kernel<<<g1, blk, 0, stream>>>(q, k, v, Wq, Wk, Wv, Qp, Kp, VpT);

    dim3 g2(Ssz / 64, Hh, Bb);
    attn_kernel<<<g2, blk, 0, stream>>>(Qp, Kp, VpT, emb, out);
}